// Round 7
// baseline (897.898 us; speedup 1.0000x reference)
//
#include <hip/hip_runtime.h>

#define NTRAIN 32768
#define NTEST  4096
#define DIM    64
#define KSEL   32
#define NLAB   1000
#define NCH    8        // j-chunks
#define CHCOLS 4096     // train cols per chunk
#define SLOT   96       // candidate slots per (test, chunk)
#define NBIN   256
#define SSAMP  4096     // sample size for threshold pass
#define SRANK2 24       // sample crossing rank -> E[full below Te] ~ 192
#define POOLCAP 1600
#define WCOEF  0.01f    // >= 0.0085 bf16 Cauchy-Schwarz bound

using short8 = __attribute__((ext_vector_type(8))) short;
using f32x4  = __attribute__((ext_vector_type(4))) float;
typedef unsigned short u16;

__device__ __forceinline__ unsigned f2u(float f){
  unsigned b = __float_as_uint(f);
  return (b & 0x80000000u) ? ~b : (b | 0x80000000u);
}
// fp32 -> bf16 round-to-nearest-even
__device__ __forceinline__ u16 f2b(float x){
  unsigned u = __float_as_uint(x);
  return (u16)((u + 0x7fffu + ((u >> 16) & 1u)) >> 16);
}

struct Sel {
  unsigned hist[2048];
  unsigned wsum[4];
  unsigned sB, sLess, sU;
  int sNeed;
};

// exact value of the rank-th smallest key (1-based) among keys[0..n). n>=rank.
__device__ unsigned radix_select(const unsigned* __restrict__ keys, int n,
                                 unsigned rank, Sel* s, int t, int* needOut)
{
  const int lane = t & 63, wid = t >> 6;
  unsigned target = rank, pref = 0;
  for (int lev = 0; lev < 3; ++lev){
    const int nb    = (lev == 2) ? 1024 : 2048;
    const int shift = (lev == 0) ? 21 : (lev == 1 ? 10 : 0);
    for (int q = t; q < nb; q += 256) s->hist[q] = 0;
    __syncthreads();
    for (int i = t; i < n; i += 256){
      unsigned u = keys[i];
      bool ok = (lev == 0) ? true
              : (lev == 1) ? ((u >> 21) == pref)
                           : ((u >> 10) == pref);
      if (ok) atomicAdd(&s->hist[(u >> shift) & (unsigned)(nb - 1)], 1u);
    }
    __syncthreads();
    const int g = nb / 256;
    unsigned sl = 0;
#pragma unroll
    for (int k = 0; k < 8; ++k) if (k < g) sl += s->hist[t*g + k];
    unsigned x = sl;
#pragma unroll
    for (int ofs = 1; ofs < 64; ofs <<= 1){
      unsigned v = __shfl_up(x, (unsigned)ofs, 64);
      if (lane >= ofs) x += v;
    }
    if (lane == 63) s->wsum[wid] = x;
    __syncthreads();
    unsigned woff = 0;
#pragma unroll
    for (int w = 0; w < 4; ++w) if (w < wid) woff += s->wsum[w];
    unsigned incl = x + woff;
    unsigned excl = incl - sl;
    if (excl < target && target <= incl){
      unsigned cum = excl; int b = t*g;
      while (cum + s->hist[b] < target){ cum += s->hist[b]; ++b; }
      s->sB = (unsigned)b; s->sLess = cum;
    }
    __syncthreads();
    unsigned B = s->sB, cl = s->sLess;
    target -= cl;
    if      (lev == 0) pref = B;
    else if (lev == 1) pref = (pref << 11) | B;
    else if (t == 0){ s->sU = (pref << 10) | B; s->sNeed = (int)target; }
  }
  __syncthreads();
  *needOut = s->sNeed;
  return s->sU;
}

// exact top-KSEL among (ku,ki)[0..n) by (key asc, idx asc). n>=KSEL. writes selI.
__device__ void select32(const unsigned* ku, const unsigned* ki, int n,
                         Sel* s, unsigned* tieI, unsigned* selI,
                         int* selCnt, int* tieCnt, int t)
{
  int need;
  unsigned ustar = radix_select(ku, n, KSEL, s, t, &need);
  if (t == 0){ *selCnt = 0; *tieCnt = 0; }
  __syncthreads();
  for (int i = t; i < n; i += 256){
    unsigned u = ku[i];
    if (u < ustar){ int p = atomicAdd(selCnt, 1); if (p < 40) selI[p] = ki[i]; }
    else if (u == ustar){ int p = atomicAdd(tieCnt, 1); if (p < 256) tieI[p] = ki[i]; }
  }
  __syncthreads();
  int nT = *tieCnt; if (nT > 256) nT = 256;
  if (t < nT){
    unsigned my = tieI[t]; int r = 0;
    for (int k = 0; k < nT; ++k) r += (tieI[k] < my) ? 1 : 0;
    if (r < need){ int p = atomicAdd(selCnt, 1); if (p < 40) selI[p] = my; }
  }
  __syncthreads();
}

// ---- calib: measure MFMA output-slot -> (A-index, B-index) mapping ----
__global__ void calib(int* __restrict__ MT, int* __restrict__ JT,
                      int* __restrict__ okf)
{
  const int l = threadIdx.x;          // 64 threads = 1 wave
  const int v = l & 15;
  short8 av, onev, kv;
  u16 vb  = f2b((float)(v + 1));
  u16 one = (u16)0x3F80;
#pragma unroll
  for (int e = 0; e < 8; ++e){
    ((u16*)&av)[e]   = vb;
    ((u16*)&onev)[e] = one;
    ((u16*)&kv)[e]   = f2b((float)((l >> 4)*8 + e + 1));
  }
  f32x4 dA = {0,0,0,0}, dB = {0,0,0,0}, dK = {0,0,0,0};
  dA = __builtin_amdgcn_mfma_f32_16x16x32_bf16(av, onev, dA, 0,0,0);
  dB = __builtin_amdgcn_mfma_f32_16x16x32_bf16(onev, av, dB, 0,0,0);
  dK = __builtin_amdgcn_mfma_f32_16x16x32_bf16(kv, kv, dK, 0,0,0);
  bool ok = true;
#pragma unroll
  for (int e = 0; e < 4; ++e){
    int mi = (int)(dA[e]*(1.0f/32.0f) + 0.5f) - 1;
    int ji = (int)(dB[e]*(1.0f/32.0f) + 0.5f) - 1;
    if (mi < 0 || mi > 15 || dA[e] != 32.0f*(float)(mi+1)) ok = false;
    if (ji < 0 || ji > 15 || dB[e] != 32.0f*(float)(ji+1)) ok = false;
    if (dK[e] != 11440.0f) ok = false;
    MT[l*4 + e] = mi & 15;
    JT[l*4 + e] = ji & 15;
  }
  unsigned long long bal = __ballot(ok);
  if (l == 0) okf[0] = (bal == ~0ull) ? 1 : 0;
}

// ---- prep: x_train -> bf16 + hb2 = 0.5*||b||^2 + stats {sum, sumsq, maxb2} ----
__global__ __launch_bounds__(256) void prep(const float* __restrict__ xtr,
        u16* __restrict__ xtr16, float* __restrict__ hb2,
        float* __restrict__ stats)
{
  int j = blockIdx.x*256 + threadIdx.x;
  const float4* rp = (const float4*)(xtr + (size_t)j*DIM);
  u16* orow = xtr16 + (size_t)j*DIM;
  float s = 0.f;
#pragma unroll
  for (int q = 0; q < 16; ++q){
    float4 w = rp[q];
    uint2 pk;
    pk.x = (unsigned)f2b(w.x) | ((unsigned)f2b(w.y) << 16);
    pk.y = (unsigned)f2b(w.z) | ((unsigned)f2b(w.w) << 16);
    *(uint2*)(orow + q*4) = pk;
    s = fmaf(w.x,w.x,s); s = fmaf(w.y,w.y,s);
    s = fmaf(w.z,w.z,s); s = fmaf(w.w,w.w,s);
  }
  float hs = 0.5f * s;
  hb2[j] = hs;
  float r0 = hs, r1 = hs*hs, r2 = s;
#pragma unroll
  for (int msk = 1; msk < 64; msk <<= 1){
    r0 += __shfl_xor(r0, msk, 64);
    r1 += __shfl_xor(r1, msk, 64);
    r2 = fmaxf(r2, __shfl_xor(r2, msk, 64));
  }
  if ((threadIdx.x & 63) == 0){
    atomicAdd(&stats[0], r0);
    atomicAdd(&stats[1], r1);
    atomicMax((unsigned*)&stats[2], __float_as_uint(r2));
  }
}

// ---- prepT: x_test -> bf16 + per-test binning params lo/scale + W ----
__global__ __launch_bounds__(256) void prepT(const float* __restrict__ xtst,
        u16* __restrict__ xtst16, const float* __restrict__ stats,
        float* __restrict__ loT, float* __restrict__ bsT, float* __restrict__ Wt)
{
  int m = blockIdx.x*256 + threadIdx.x;
  const float4* rp = (const float4*)(xtst + (size_t)m*DIM);
  u16* orow = xtst16 + (size_t)m*DIM;
  float s = 0.f;
#pragma unroll
  for (int q = 0; q < 16; ++q){
    float4 w = rp[q];
    uint2 pk;
    pk.x = (unsigned)f2b(w.x) | ((unsigned)f2b(w.y) << 16);
    pk.y = (unsigned)f2b(w.z) | ((unsigned)f2b(w.w) << 16);
    *(uint2*)(orow + q*4) = pk;
    s = fmaf(w.x,w.x,s); s = fmaf(w.y,w.y,s);
    s = fmaf(w.z,w.z,s); s = fmaf(w.w,w.w,s);
  }
  const float invN = 1.0f/(float)NTRAIN;
  float C   = stats[0]*invN;
  float var = fmaxf(stats[1]*invN - C*C, 0.f);
  float mb  = __uint_as_float(*(const unsigned*)&stats[2]);
  float sig = sqrtf(var + s) + 1e-6f;
  loT[m] = C - 12.f*sig;
  bsT[m] = 16.f/sig;               // 256 bins spanning 16*sig
  Wt[m]  = WCOEF * sqrtf(s * mb);
}

// ---- sampleT: per-test threshold from first SSAMP train pts (MFMA + LDS hist,
//      skip-cutoff so only ~2% of keys take an LDS atomic) ----
__global__ __launch_bounds__(256) void sampleT(const u16* __restrict__ xtr16,
        const u16* __restrict__ xtst16, const float* __restrict__ hb2,
        const float* __restrict__ loT, const float* __restrict__ bsT,
        const float* __restrict__ Wt, const int* __restrict__ MT,
        const int* __restrict__ JT, const int* __restrict__ okf,
        float* __restrict__ TfB, float* __restrict__ thrFB)
{
  __shared__ unsigned histL[16*NBIN];   // 16 KB
  __shared__ float hbS[SSAMP];          // 16 KB

  const int t = threadIdx.x, lane = t & 63, w = t >> 6;
  const int m0 = blockIdx.x * 16;
  if (okf[0] == 0){
    if (t < 16){ TfB[m0+t] = 0.f; thrFB[m0+t] = -3.0e38f; }   // -> fallback
    return;
  }
  const int oprow = lane & 15, kgrp = lane >> 4;

  for (int i = t; i < 16*NBIN; i += 256) histL[i] = 0;
  for (int i = t; i < SSAMP; i += 256) hbS[i] = hb2[i];

  int Ml[4], Jl[4];
#pragma unroll
  for (int e = 0; e < 4; ++e){ Ml[e] = MT[lane*4+e]; Jl[e] = JT[lane*4+e]; }

  const u16* ap = xtst16 + (size_t)(m0 + oprow)*DIM + kgrp*8;
  short8 a00 = *(const short8*)ap;
  short8 a01 = *(const short8*)(ap + 32);

  float lo0[4], bs0[4];
#pragma unroll
  for (int e = 0; e < 4; ++e){
    lo0[e] = loT[m0 + Ml[e]]; bs0[e] = bsT[m0 + Ml[e]];
  }
  __syncthreads();

  const int wcol = w*1024;
  const u16* bp = xtr16 + (size_t)(wcol + oprow)*DIM + kgrp*8;

#pragma unroll 2
  for (int jt = 0; jt < 64; ++jt){
    short8 b0 = *(const short8*)bp;
    short8 b1 = *(const short8*)(bp + 32);
    f32x4 c0 = {0.f,0.f,0.f,0.f};
    c0 = __builtin_amdgcn_mfma_f32_16x16x32_bf16(a00, b0, c0, 0,0,0);
    c0 = __builtin_amdgcn_mfma_f32_16x16x32_bf16(a01, b1, c0, 0,0,0);
    const int jl = wcol + jt*16;
#pragma unroll
    for (int e = 0; e < 4; ++e){
      float h = hbS[jl + Jl[e]];
      float f = (h - c0[e] - lo0[e]) * bs0[e];
      if (f < 161.f){                         // skip: bins >160 can't matter
        int b = (f < 0.f) ? 0 : (int)f;
        atomicAdd(&histL[Ml[e]*NBIN + b], 1u);
      }
    }
    bp += 16*DIM;
  }
  __syncthreads();
  if (t < 16){
    const unsigned* h = &histL[t*NBIN];
    unsigned cum = 0; int b = -1;
    for (int i = 0; i <= 160; ++i){
      cum += h[i];
      if (cum >= SRANK2){ b = i; break; }
    }
    int m = m0 + t;
    if (b < 0){ TfB[m] = 0.f; thrFB[m] = -3.0e38f; }   // -> empty -> fallback
    else {
      float Te = loT[m] + (float)(b + 1) / bsT[m];
      float Wv = Wt[m];
      TfB[m]   = Te + 1.5f*Wv;
      thrFB[m] = Te + 2.5f*Wv;
    }
  }
}

// ---- knnA: MFMA filter, LDS slot buffers, zero global atomics ----
__global__ __launch_bounds__(256) void knnA(const u16* __restrict__ xtr16,
        const u16* __restrict__ xtst16, const float* __restrict__ hb2,
        const float* __restrict__ thrFB, const int* __restrict__ MT,
        const int* __restrict__ JT, const int* __restrict__ okf,
        unsigned* __restrict__ cnt2, unsigned* __restrict__ cand)
{
  __shared__ float hbS[CHCOLS];          // 16 KB
  __shared__ unsigned lbuf[32][SLOT];    // 12 KB
  __shared__ unsigned lcnt[32];

  const int t = threadIdx.x, lane = t & 63, w = t >> 6;
  const int jc = blockIdx.x & 7, mg = blockIdx.x >> 3;
  const int m0 = mg*32, col0 = jc*CHCOLS;

  if (okf[0] == 0){
    if (t < 32) cnt2[(size_t)jc*NTEST + m0 + t] = 0xFFFFFFFFu;  // force fallback
    return;
  }
  const int oprow = lane & 15, kgrp = lane >> 4;

  if (t < 32) lcnt[t] = 0;
  for (int i = t; i < CHCOLS; i += 256) hbS[i] = hb2[col0 + i];

  int Ml[4], Jl[4];
#pragma unroll
  for (int e = 0; e < 4; ++e){ Ml[e] = MT[lane*4+e]; Jl[e] = JT[lane*4+e]; }

  const u16* ap = xtst16 + (size_t)(m0 + oprow)*DIM + kgrp*8;
  short8 a00 = *(const short8*)ap;
  short8 a01 = *(const short8*)(ap + 32);
  short8 a10 = *(const short8*)(ap + 16*DIM);
  short8 a11 = *(const short8*)(ap + 16*DIM + 32);

  float th0[4], th1[4];
#pragma unroll
  for (int e = 0; e < 4; ++e){
    th0[e] = thrFB[m0 + Ml[e]];
    th1[e] = thrFB[m0 + 16 + Ml[e]];
  }
  float tm0 = fmaxf(fmaxf(th0[0],th0[1]), fmaxf(th0[2],th0[3]));
  float tm1 = fmaxf(fmaxf(th1[0],th1[1]), fmaxf(th1[2],th1[3]));

  __syncthreads();

  const int wcol = w*1024;
  const u16* bp = xtr16 + (size_t)(col0 + wcol + oprow)*DIM + kgrp*8;

#pragma unroll 2
  for (int jt = 0; jt < 64; ++jt){
    short8 b0 = *(const short8*)bp;
    short8 b1 = *(const short8*)(bp + 32);
    f32x4 c0 = {0.f,0.f,0.f,0.f}, c1 = {0.f,0.f,0.f,0.f};
    c0 = __builtin_amdgcn_mfma_f32_16x16x32_bf16(a00, b0, c0, 0,0,0);
    c0 = __builtin_amdgcn_mfma_f32_16x16x32_bf16(a01, b1, c0, 0,0,0);
    c1 = __builtin_amdgcn_mfma_f32_16x16x32_bf16(a10, b0, c1, 0,0,0);
    c1 = __builtin_amdgcn_mfma_f32_16x16x32_bf16(a11, b1, c1, 0,0,0);
    const int jl = wcol + jt*16;
    float h[4];
#pragma unroll
    for (int e = 0; e < 4; ++e) h[e] = hbS[jl + Jl[e]];
    float g0 = fmaxf(fmaxf(c0[0]-h[0], c0[1]-h[1]), fmaxf(c0[2]-h[2], c0[3]-h[3]));
    if (g0 + tm0 > 0.f){
#pragma unroll
      for (int e = 0; e < 4; ++e) if (h[e] - c0[e] < th0[e]){
        unsigned p = atomicAdd(&lcnt[Ml[e]], 1u);
        if (p < SLOT) lbuf[Ml[e]][p] = (unsigned)(col0 + jl + Jl[e]);
      }
    }
    float g1 = fmaxf(fmaxf(c1[0]-h[0], c1[1]-h[1]), fmaxf(c1[2]-h[2], c1[3]-h[3]));
    if (g1 + tm1 > 0.f){
#pragma unroll
      for (int e = 0; e < 4; ++e) if (h[e] - c1[e] < th1[e]){
        unsigned p = atomicAdd(&lcnt[16 + Ml[e]], 1u);
        if (p < SLOT) lbuf[16 + Ml[e]][p] = (unsigned)(col0 + jl + Jl[e]);
      }
    }
    bp += 16*DIM;
  }
  __syncthreads();
  if (t < 32) cnt2[(size_t)jc*NTEST + m0 + t] = lcnt[t];
  for (int i = t; i < 32*SLOT; i += 256){
    int ms = i / SLOT, e = i - ms*SLOT;
    cand[((size_t)(m0 + ms)*NCH + jc)*SLOT + e] = lbuf[ms][e];
  }
}

// ---- knnB: exact fp32 re-rank + verify + vote + argmax ----
__global__ __launch_bounds__(256) void knnB(const float* __restrict__ x_train,
        const float* __restrict__ hb2, const float* __restrict__ x_test,
        const int* __restrict__ y_train, const float* __restrict__ w_train,
        const float* __restrict__ TfB, const int* __restrict__ okf,
        const unsigned* __restrict__ cnt2, const unsigned* __restrict__ cand,
        int* __restrict__ out)
{
  __shared__ unsigned ku[POOLCAP], ki[POOLCAP];
  __shared__ unsigned chunkKeys[1024];
  __shared__ Sel ss;
  __shared__ unsigned tieI[256];
  __shared__ unsigned selI[40];
  __shared__ unsigned selR[KSEL];
  __shared__ int selCnt, tieCnt, poolCnt, nBelow, badJ;
  __shared__ float votes[NLAB];
  __shared__ unsigned cntS[NCH];
  __shared__ int yv[KSEL]; __shared__ float wv[KSEL];

  const int t = threadIdx.x, m = blockIdx.x;
  float a[DIM];
  const float4* am = (const float4*)(x_test + (size_t)m*DIM);
#pragma unroll
  for (int q = 0; q < 16; ++q){
    float4 v = am[q];
    a[4*q]=v.x; a[4*q+1]=v.y; a[4*q+2]=v.z; a[4*q+3]=v.w;
  }
  if (t < NCH) cntS[t] = cnt2[(size_t)t*NTEST + m];
  if (t == 0){ nBelow = 0; badJ = 0; }
  __syncthreads();

  bool ovf = (okf[0] == 0);
  unsigned offs[NCH+1]; offs[0] = 0;
#pragma unroll
  for (int jcc = 0; jcc < NCH; ++jcc){
    unsigned cc = cntS[jcc];
    if (cc > SLOT) ovf = true;
    offs[jcc+1] = offs[jcc] + ((cc > SLOT) ? SLOT : cc);
  }
  int c = (int)offs[NCH];
  bool mainok = !ovf && c >= KSEL;

  if (mainok){
#pragma unroll
    for (int jcc = 0; jcc < NCH; ++jcc){
      unsigned cc = cntS[jcc];
      for (unsigned i = t; i < cc; i += 256){
        unsigned j = cand[((size_t)m*NCH + jcc)*SLOT + i];
        if (j >= NTRAIN){ badJ = 1; j = 0; }
        ki[offs[jcc] + i] = j;
      }
    }
    __syncthreads();
    if (badJ) mainok = false;
  }
  const float Tf = TfB[m];
  if (mainok){
    for (int i = t; i < c; i += 256){
      unsigned j = ki[i];
      const float4* rp = (const float4*)(x_train + (size_t)j*DIM);
      float s = 0.f;
#pragma unroll
      for (int q = 0; q < 16; ++q){
        float4 v = rp[q];
        s = fmaf(a[4*q],v.x,s); s = fmaf(a[4*q+1],v.y,s);
        s = fmaf(a[4*q+2],v.z,s); s = fmaf(a[4*q+3],v.w,s);
      }
      float kf = hb2[j] - s;
      ku[i] = f2u(kf);
      if (kf < Tf) atomicAdd(&nBelow, 1);
    }
    __syncthreads();
    mainok = (nBelow >= KSEL);
  }

  if (mainok){
    // all-pairs exact rank by (key asc, idx asc); deterministic slot-by-rank
    for (int i = t; i < c; i += 256){
      unsigned mu = ku[i], mi = ki[i];
      int r = 0;
      for (int k = 0; k < c; ++k){
        unsigned kk = ku[k], kj = ki[k];
        r += (kk < mu || (kk == mu && kj < mi)) ? 1 : 0;
      }
      if (r < KSEL) selR[r] = mi;
    }
    __syncthreads();
  } else {
    // fallback (safety net): exact full scan, chunk top-32 pooling
    if (t == 0) poolCnt = 0;
    __syncthreads();
    for (int ch = 0; ch < NTRAIN/1024; ++ch){
      const int j0 = ch*1024;
      for (int q = 0; q < 4; ++q){
        int j = j0 + q*256 + t;
        const float4* rp = (const float4*)(x_train + (size_t)j*DIM);
        float s = 0.f;
#pragma unroll
        for (int qq = 0; qq < 16; ++qq){
          float4 v = rp[qq];
          s = fmaf(a[4*qq],v.x,s); s = fmaf(a[4*qq+1],v.y,s);
          s = fmaf(a[4*qq+2],v.z,s); s = fmaf(a[4*qq+3],v.w,s);
        }
        chunkKeys[q*256 + t] = f2u(hb2[j] - s);
      }
      __syncthreads();
      int need;
      unsigned ustar = radix_select(chunkKeys, 1024, KSEL, &ss, t, &need);
      for (int q = 0; q < 4; ++q){
        unsigned u = chunkKeys[q*256 + t];
        if (u <= ustar){
          int p = atomicAdd(&poolCnt, 1);
          if (p < POOLCAP){ ku[p] = u; ki[p] = (unsigned)(j0 + q*256 + t); }
        }
      }
      __syncthreads();
    }
    int n = poolCnt; if (n > POOLCAP) n = POOLCAP;
    select32(ku, ki, n, &ss, tieI, selI, &selCnt, &tieCnt, t);
    if (t < KSEL) selR[t] = selI[t];
    __syncthreads();
  }

  // deterministic vote: reorder selected by train idx, then serial adds
  for (int q = t; q < NLAB; q += 256) votes[q] = 0.f;
  if (t < KSEL){
    unsigned my = selR[t]; int r = 0;
#pragma unroll
    for (int k = 0; k < KSEL; ++k) r += (selR[k] < my) ? 1 : 0;
    yv[r] = y_train[my]; wv[r] = w_train[my];
  }
  __syncthreads();
  if (t == 0){
    for (int r = 0; r < KSEL; ++r) votes[yv[r]] += wv[r];
  }
  __syncthreads();

  // argmax, lowest label wins ties
  float* rv = (float*)ss.hist;
  int*   rl = (int*)(ss.hist + 256);
  float bv = -1.f; int bl = 0;
  for (int l = t; l < NLAB; l += 256){
    float v = votes[l];
    if (v > bv){ bv = v; bl = l; }
  }
  rv[t] = bv; rl[t] = bl;
  __syncthreads();
  for (int sred = 128; sred > 0; sred >>= 1){
    if (t < sred){
      if (rv[t+sred] > rv[t] || (rv[t+sred] == rv[t] && rl[t+sred] < rl[t])){
        rv[t] = rv[t+sred]; rl[t] = rl[t+sred];
      }
    }
    __syncthreads();
  }
  if (t == 0) out[m] = rl[0];
}

// ---- legacy (direct-read path): used only if ws too small ----
__global__ __launch_bounds__(256) void knn_legacy(
    const float* __restrict__ x_train, const float* __restrict__ x_test,
    const int* __restrict__ y_train, const float* __restrict__ w_train,
    int* __restrict__ out)
{
  __shared__ unsigned keys[16384];
  __shared__ Sel ss;
  __shared__ unsigned candU[64];
  __shared__ unsigned candI[64];
  __shared__ unsigned tieI[256];
  __shared__ int nCand, nTie;
  __shared__ float rv[256]; __shared__ int rl[256];

  float* votes = (float*)ss.hist;
  const int t = threadIdx.x;
  const int m = blockIdx.x;

  float a[DIM];
  const float* am = x_test + (size_t)m * DIM;
#pragma unroll
  for (int d = 0; d < DIM; ++d) a[d] = am[d];

  if (t == 0) nCand = 0;

  for (int h = 0; h < 2; ++h){
    __syncthreads();
    for (int i = 0; i < 64; ++i){
      int j = h*16384 + i*256 + t;
      const float4* bp = (const float4*)(x_train + (size_t)j * DIM);
      float s = 0.f;
#pragma unroll
      for (int q = 0; q < 16; ++q){
        float4 v = bp[q];
        float e0 = a[4*q]   - v.x, e1 = a[4*q+1] - v.y;
        float e2 = a[4*q+2] - v.z, e3 = a[4*q+3] - v.w;
        s = fmaf(e0,e0,s); s = fmaf(e1,e1,s); s = fmaf(e2,e2,s); s = fmaf(e3,e3,s);
      }
      keys[i*256 + t] = f2u(s);
    }
    __syncthreads();

    int need;
    unsigned ustar = radix_select(keys, 16384, KSEL, &ss, t, &need);
    if (t == 0) nTie = 0;
    __syncthreads();

    for (int i = 0; i < 64; ++i){
      unsigned u   = keys[i*256 + t];
      unsigned idx = (unsigned)(h*16384 + i*256 + t);
      if (u < ustar){
        int p = atomicAdd(&nCand, 1);
        if (p < 64){ candU[p] = u; candI[p] = idx; }
      } else if (u == ustar){
        int p = atomicAdd(&nTie, 1);
        if (p < 256) tieI[p] = idx;
      }
    }
    __syncthreads();
    int nT = nTie; if (nT > 256) nT = 256;
    if (t < nT){
      unsigned my = tieI[t]; int r = 0;
      for (int k = 0; k < nT; ++k) r += (tieI[k] < my) ? 1 : 0;
      if (r < need){
        int p = atomicAdd(&nCand, 1);
        if (p < 64){ candU[p] = ustar; candI[p] = my; }
      }
    }
    __syncthreads();
  }

  for (int q = t; q < NLAB; q += 256) votes[q] = 0.f;
  __syncthreads();
  int nC = nCand; if (nC > 64) nC = 64;
  if (t < nC){
    unsigned mu = candU[t], mi = candI[t];
    int r = 0;
    for (int k = 0; k < nC; ++k){
      unsigned kku = candU[k], kki = candI[k];
      r += (kku < mu || (kku == mu && kki < mi)) ? 1 : 0;
    }
    if (r < KSEL){
      int lab = y_train[mi];
      atomicAdd(&votes[lab], w_train[mi]);
    }
  }
  __syncthreads();

  float bv = -1.f; int bl = 0;
  for (int l = t; l < NLAB; l += 256){
    float v = votes[l];
    if (v > bv){ bv = v; bl = l; }
  }
  rv[t] = bv; rl[t] = bl;
  __syncthreads();
  for (int s = 128; s > 0; s >>= 1){
    if (t < s){
      if (rv[t+s] > rv[t] || (rv[t+s] == rv[t] && rl[t+s] < rl[t])){
        rv[t] = rv[t+s]; rl[t] = rl[t+s];
      }
    }
    __syncthreads();
  }
  if (t == 0) out[m] = rl[0];
}

extern "C" void kernel_launch(void* const* d_in, const int* in_sizes, int n_in,
                              void* d_out, int out_size, void* d_ws, size_t ws_size,
                              hipStream_t stream)
{
  (void)in_sizes; (void)n_in; (void)out_size;
  const float* x_train = (const float*)d_in[0];
  const int*   y_train = (const int*)  d_in[1];
  const float* x_test  = (const float*)d_in[2];
  const float* w_train = (const float*)d_in[3];
  int* out = (int*)d_out;

  char* p = (char*)d_ws;
  u16*      xtr16  = (u16*)p;      p += (size_t)NTRAIN*DIM*2;
  u16*      xtst16 = (u16*)p;      p += (size_t)NTEST*DIM*2;
  float*    hb2    = (float*)p;    p += (size_t)NTRAIN*4;
  float*    loT    = (float*)p;    p += (size_t)NTEST*4;
  float*    bsT    = (float*)p;    p += (size_t)NTEST*4;
  float*    Wt     = (float*)p;    p += (size_t)NTEST*4;
  float*    TfB    = (float*)p;    p += (size_t)NTEST*4;
  float*    thrFB  = (float*)p;    p += (size_t)NTEST*4;
  unsigned* cnt2   = (unsigned*)p; p += (size_t)NCH*NTEST*4;
  int*      MT     = (int*)p;      p += 64*4*4;
  int*      JT     = (int*)p;      p += 64*4*4;
  int*      okf    = (int*)p;      p += 256;
  float*    stats  = (float*)p;    p += 512;
  unsigned* cand   = (unsigned*)p; p += (size_t)NTEST*NCH*SLOT*4;
  size_t need = (size_t)(p - (char*)d_ws);

  if (ws_size >= need){
    hipMemsetAsync(stats, 0, 512, stream);
    calib<<<1, 64, 0, stream>>>(MT, JT, okf);
    prep <<<NTRAIN/256, 256, 0, stream>>>(x_train, xtr16, hb2, stats);
    prepT<<<NTEST/256,  256, 0, stream>>>(x_test, xtst16, stats, loT, bsT, Wt);
    sampleT<<<NTEST/16, 256, 0, stream>>>(xtr16, xtst16, hb2, loT, bsT, Wt,
                                          MT, JT, okf, TfB, thrFB);
    knnA<<<(NTEST/32)*NCH, 256, 0, stream>>>(xtr16, xtst16, hb2, thrFB,
                                             MT, JT, okf, cnt2, cand);
    knnB<<<NTEST, 256, 0, stream>>>(x_train, hb2, x_test, y_train, w_train,
                                    TfB, okf, cnt2, cand, out);
  } else {
    knn_legacy<<<NTEST, 256, 0, stream>>>(x_train, x_test, y_train, w_train, out);
  }
}

// Round 8
// 337.550 us; speedup vs baseline: 2.6600x; 2.6600x over previous
//
#include <hip/hip_runtime.h>

#define NTRAIN 32768
#define NTEST  4096
#define DIM    64
#define KSEL   32
#define NLAB   1000
#define NCH    8        // j-chunks
#define CHCOLS 4096     // train cols per chunk
#define SLOT   224      // candidate slots per (test, chunk), u16 local idx
#define NBIN   256
#define SSAMP  8192     // sample size for threshold pass (chunks 0-1)
#define SRANK2 32       // >= KSEL: deterministic verification guarantee
#define POOLCAP 1792    // >= NCH*SLOT
#define WCOEF  0.01f    // >= 0.0078 bf16 Cauchy-Schwarz bound + margin

using short8 = __attribute__((ext_vector_type(8))) short;
using f32x4  = __attribute__((ext_vector_type(4))) float;
typedef unsigned short u16;

__device__ __forceinline__ unsigned f2u(float f){
  unsigned b = __float_as_uint(f);
  return (b & 0x80000000u) ? ~b : (b | 0x80000000u);
}
// fp32 -> bf16 round-to-nearest-even
__device__ __forceinline__ u16 f2b(float x){
  unsigned u = __float_as_uint(x);
  return (u16)((u + 0x7fffu + ((u >> 16) & 1u)) >> 16);
}

struct Sel {
  unsigned hist[2048];
  unsigned wsum[4];
  unsigned sB, sLess, sU;
  int sNeed;
};

// exact value of the rank-th smallest key (1-based) among keys[0..n). n>=rank.
__device__ unsigned radix_select(const unsigned* __restrict__ keys, int n,
                                 unsigned rank, Sel* s, int t, int* needOut)
{
  const int lane = t & 63, wid = t >> 6;
  unsigned target = rank, pref = 0;
  for (int lev = 0; lev < 3; ++lev){
    const int nb    = (lev == 2) ? 1024 : 2048;
    const int shift = (lev == 0) ? 21 : (lev == 1 ? 10 : 0);
    for (int q = t; q < nb; q += 256) s->hist[q] = 0;
    __syncthreads();
    for (int i = t; i < n; i += 256){
      unsigned u = keys[i];
      bool ok = (lev == 0) ? true
              : (lev == 1) ? ((u >> 21) == pref)
                           : ((u >> 10) == pref);
      if (ok) atomicAdd(&s->hist[(u >> shift) & (unsigned)(nb - 1)], 1u);
    }
    __syncthreads();
    const int g = nb / 256;
    unsigned sl = 0;
#pragma unroll
    for (int k = 0; k < 8; ++k) if (k < g) sl += s->hist[t*g + k];
    unsigned x = sl;
#pragma unroll
    for (int ofs = 1; ofs < 64; ofs <<= 1){
      unsigned v = __shfl_up(x, (unsigned)ofs, 64);
      if (lane >= ofs) x += v;
    }
    if (lane == 63) s->wsum[wid] = x;
    __syncthreads();
    unsigned woff = 0;
#pragma unroll
    for (int w = 0; w < 4; ++w) if (w < wid) woff += s->wsum[w];
    unsigned incl = x + woff;
    unsigned excl = incl - sl;
    if (excl < target && target <= incl){
      unsigned cum = excl; int b = t*g;
      while (cum + s->hist[b] < target){ cum += s->hist[b]; ++b; }
      s->sB = (unsigned)b; s->sLess = cum;
    }
    __syncthreads();
    unsigned B = s->sB, cl = s->sLess;
    target -= cl;
    if      (lev == 0) pref = B;
    else if (lev == 1) pref = (pref << 11) | B;
    else if (t == 0){ s->sU = (pref << 10) | B; s->sNeed = (int)target; }
  }
  __syncthreads();
  *needOut = s->sNeed;
  return s->sU;
}

// exact top-KSEL among (ku,ki)[0..n) by (key asc, idx asc). n>=KSEL. writes selI.
__device__ void select32(const unsigned* ku, const unsigned* ki, int n,
                         Sel* s, unsigned* tieI, unsigned* selI,
                         int* selCnt, int* tieCnt, int t)
{
  int need;
  unsigned ustar = radix_select(ku, n, KSEL, s, t, &need);
  if (t == 0){ *selCnt = 0; *tieCnt = 0; }
  __syncthreads();
  for (int i = t; i < n; i += 256){
    unsigned u = ku[i];
    if (u < ustar){ int p = atomicAdd(selCnt, 1); if (p < 40) selI[p] = ki[i]; }
    else if (u == ustar){ int p = atomicAdd(tieCnt, 1); if (p < 256) tieI[p] = ki[i]; }
  }
  __syncthreads();
  int nT = *tieCnt; if (nT > 256) nT = 256;
  if (t < nT){
    unsigned my = tieI[t]; int r = 0;
    for (int k = 0; k < nT; ++k) r += (tieI[k] < my) ? 1 : 0;
    if (r < need){ int p = atomicAdd(selCnt, 1); if (p < 40) selI[p] = my; }
  }
  __syncthreads();
}

// ---- calib: measure MFMA output-slot -> (A-index, B-index) mapping ----
__global__ void calib(int* __restrict__ MT, int* __restrict__ JT,
                      int* __restrict__ okf)
{
  const int l = threadIdx.x;          // 64 threads = 1 wave
  const int v = l & 15;
  short8 av, onev, kv;
  u16 vb  = f2b((float)(v + 1));
  u16 one = (u16)0x3F80;
#pragma unroll
  for (int e = 0; e < 8; ++e){
    ((u16*)&av)[e]   = vb;
    ((u16*)&onev)[e] = one;
    ((u16*)&kv)[e]   = f2b((float)((l >> 4)*8 + e + 1));
  }
  f32x4 dA = {0,0,0,0}, dB = {0,0,0,0}, dK = {0,0,0,0};
  dA = __builtin_amdgcn_mfma_f32_16x16x32_bf16(av, onev, dA, 0,0,0);
  dB = __builtin_amdgcn_mfma_f32_16x16x32_bf16(onev, av, dB, 0,0,0);
  dK = __builtin_amdgcn_mfma_f32_16x16x32_bf16(kv, kv, dK, 0,0,0);
  bool ok = true;
#pragma unroll
  for (int e = 0; e < 4; ++e){
    int mi = (int)(dA[e]*(1.0f/32.0f) + 0.5f) - 1;
    int ji = (int)(dB[e]*(1.0f/32.0f) + 0.5f) - 1;
    if (mi < 0 || mi > 15 || dA[e] != 32.0f*(float)(mi+1)) ok = false;
    if (ji < 0 || ji > 15 || dB[e] != 32.0f*(float)(ji+1)) ok = false;
    if (dK[e] != 11440.0f) ok = false;
    MT[l*4 + e] = mi & 15;
    JT[l*4 + e] = ji & 15;
  }
  unsigned long long bal = __ballot(ok);
  if (l == 0) okf[0] = (bal == ~0ull) ? 1 : 0;
}

// ---- prep: x_train -> bf16 + hb2 = 0.5*||b||^2 + stats {sum, sumsq, maxb2} ----
__global__ __launch_bounds__(256) void prep(const float* __restrict__ xtr,
        u16* __restrict__ xtr16, float* __restrict__ hb2,
        float* __restrict__ stats)
{
  int j = blockIdx.x*256 + threadIdx.x;
  const float4* rp = (const float4*)(xtr + (size_t)j*DIM);
  u16* orow = xtr16 + (size_t)j*DIM;
  float s = 0.f;
#pragma unroll
  for (int q = 0; q < 16; ++q){
    float4 w = rp[q];
    uint2 pk;
    pk.x = (unsigned)f2b(w.x) | ((unsigned)f2b(w.y) << 16);
    pk.y = (unsigned)f2b(w.z) | ((unsigned)f2b(w.w) << 16);
    *(uint2*)(orow + q*4) = pk;
    s = fmaf(w.x,w.x,s); s = fmaf(w.y,w.y,s);
    s = fmaf(w.z,w.z,s); s = fmaf(w.w,w.w,s);
  }
  float hs = 0.5f * s;
  hb2[j] = hs;
  float r0 = hs, r1 = hs*hs, r2 = s;
#pragma unroll
  for (int msk = 1; msk < 64; msk <<= 1){
    r0 += __shfl_xor(r0, msk, 64);
    r1 += __shfl_xor(r1, msk, 64);
    r2 = fmaxf(r2, __shfl_xor(r2, msk, 64));
  }
  if ((threadIdx.x & 63) == 0){
    atomicAdd(&stats[0], r0);
    atomicAdd(&stats[1], r1);
    atomicMax((unsigned*)&stats[2], __float_as_uint(r2));
  }
}

// ---- prepT: x_test -> bf16 + per-test binning params lo/scale + W ----
__global__ __launch_bounds__(256) void prepT(const float* __restrict__ xtst,
        u16* __restrict__ xtst16, const float* __restrict__ stats,
        float* __restrict__ loT, float* __restrict__ bsT, float* __restrict__ Wt)
{
  int m = blockIdx.x*256 + threadIdx.x;
  const float4* rp = (const float4*)(xtst + (size_t)m*DIM);
  u16* orow = xtst16 + (size_t)m*DIM;
  float s = 0.f;
#pragma unroll
  for (int q = 0; q < 16; ++q){
    float4 w = rp[q];
    uint2 pk;
    pk.x = (unsigned)f2b(w.x) | ((unsigned)f2b(w.y) << 16);
    pk.y = (unsigned)f2b(w.z) | ((unsigned)f2b(w.w) << 16);
    *(uint2*)(orow + q*4) = pk;
    s = fmaf(w.x,w.x,s); s = fmaf(w.y,w.y,s);
    s = fmaf(w.z,w.z,s); s = fmaf(w.w,w.w,s);
  }
  const float invN = 1.0f/(float)NTRAIN;
  float C   = stats[0]*invN;
  float var = fmaxf(stats[1]*invN - C*C, 0.f);
  float mb  = __uint_as_float(*(const unsigned*)&stats[2]);
  float sig = sqrtf(var + s) + 1e-6f;
  loT[m] = C - 12.f*sig;
  bsT[m] = 16.f/sig;               // 256 bins spanning 16*sig
  Wt[m]  = WCOEF * sqrtf(s * mb);
}

// ---- sampleT: per-test threshold from first SSAMP train pts (MFMA + LDS hist,
//      skip-cutoff so only ~2-3% of keys take an LDS atomic).
//      SRANK2 >= KSEL -> deterministic verification guarantee in knnB. ----
__global__ __launch_bounds__(256) void sampleT(const u16* __restrict__ xtr16,
        const u16* __restrict__ xtst16, const float* __restrict__ hb2,
        const float* __restrict__ loT, const float* __restrict__ bsT,
        const float* __restrict__ Wt, const int* __restrict__ MT,
        const int* __restrict__ JT, const int* __restrict__ okf,
        float* __restrict__ TfB, float* __restrict__ thrFB)
{
  __shared__ unsigned histL[16*NBIN];   // 16 KB
  __shared__ float hbS[SSAMP];          // 32 KB

  const int t = threadIdx.x, lane = t & 63, w = t >> 6;
  const int m0 = blockIdx.x * 16;
  if (okf[0] == 0){
    if (t < 16){ TfB[m0+t] = 0.f; thrFB[m0+t] = -3.0e38f; }   // -> fallback
    return;
  }
  const int oprow = lane & 15, kgrp = lane >> 4;

  for (int i = t; i < 16*NBIN; i += 256) histL[i] = 0;
  for (int i = t; i < SSAMP; i += 256) hbS[i] = hb2[i];

  int Ml[4], Jl[4];
#pragma unroll
  for (int e = 0; e < 4; ++e){ Ml[e] = MT[lane*4+e]; Jl[e] = JT[lane*4+e]; }

  const u16* ap = xtst16 + (size_t)(m0 + oprow)*DIM + kgrp*8;
  short8 a00 = *(const short8*)ap;
  short8 a01 = *(const short8*)(ap + 32);

  float lo0[4], bs0[4];
#pragma unroll
  for (int e = 0; e < 4; ++e){
    lo0[e] = loT[m0 + Ml[e]]; bs0[e] = bsT[m0 + Ml[e]];
  }
  __syncthreads();

  const int wcol = w*(SSAMP/4);
  const u16* bp = xtr16 + (size_t)(wcol + oprow)*DIM + kgrp*8;

#pragma unroll 2
  for (int jt = 0; jt < SSAMP/64; ++jt){
    short8 b0 = *(const short8*)bp;
    short8 b1 = *(const short8*)(bp + 32);
    f32x4 c0 = {0.f,0.f,0.f,0.f};
    c0 = __builtin_amdgcn_mfma_f32_16x16x32_bf16(a00, b0, c0, 0,0,0);
    c0 = __builtin_amdgcn_mfma_f32_16x16x32_bf16(a01, b1, c0, 0,0,0);
    const int jl = wcol + jt*16;
#pragma unroll
    for (int e = 0; e < 4; ++e){
      float h = hbS[jl + Jl[e]];
      float f = (h - c0[e] - lo0[e]) * bs0[e];
      if (f < 161.f){                         // skip: bins >160 can't matter
        int b = (f < 0.f) ? 0 : (int)f;
        atomicAdd(&histL[Ml[e]*NBIN + b], 1u);
      }
    }
    bp += 16*DIM;
  }
  __syncthreads();
  if (t < 16){
    const unsigned* h = &histL[t*NBIN];
    unsigned cum = 0; int b = -1;
    for (int i = 0; i <= 160; ++i){
      cum += h[i];
      if (cum >= SRANK2){ b = i; break; }
    }
    int m = m0 + t;
    if (b < 0){ TfB[m] = 0.f; thrFB[m] = -3.0e38f; }   // -> empty -> fallback
    else {
      float Te = loT[m] + (float)(b + 1) / bsT[m];
      float Wv = Wt[m];
      TfB[m]   = Te + 1.5f*Wv;
      thrFB[m] = Te + 2.5f*Wv;
    }
  }
}

// ---- knnA: MFMA filter, u16 LDS slot buffers, zero global atomics ----
__global__ __launch_bounds__(256) void knnA(const u16* __restrict__ xtr16,
        const u16* __restrict__ xtst16, const float* __restrict__ hb2,
        const float* __restrict__ thrFB, const int* __restrict__ MT,
        const int* __restrict__ JT, const int* __restrict__ okf,
        unsigned* __restrict__ cnt2, u16* __restrict__ cand)
{
  __shared__ float hbS[CHCOLS];          // 16 KB
  __shared__ u16 lbuf[32][SLOT];         // 14 KB
  __shared__ unsigned lcnt[32];

  const int t = threadIdx.x, lane = t & 63, w = t >> 6;
  const int jc = blockIdx.x & 7, mg = blockIdx.x >> 3;
  const int m0 = mg*32, col0 = jc*CHCOLS;

  if (okf[0] == 0){
    if (t < 32) cnt2[(size_t)jc*NTEST + m0 + t] = 0xFFFFFFFFu;  // force fallback
    return;
  }
  const int oprow = lane & 15, kgrp = lane >> 4;

  if (t < 32) lcnt[t] = 0;
  for (int i = t; i < CHCOLS; i += 256) hbS[i] = hb2[col0 + i];

  int Ml[4], Jl[4];
#pragma unroll
  for (int e = 0; e < 4; ++e){ Ml[e] = MT[lane*4+e]; Jl[e] = JT[lane*4+e]; }

  const u16* ap = xtst16 + (size_t)(m0 + oprow)*DIM + kgrp*8;
  short8 a00 = *(const short8*)ap;
  short8 a01 = *(const short8*)(ap + 32);
  short8 a10 = *(const short8*)(ap + 16*DIM);
  short8 a11 = *(const short8*)(ap + 16*DIM + 32);

  float th0[4], th1[4];
#pragma unroll
  for (int e = 0; e < 4; ++e){
    th0[e] = thrFB[m0 + Ml[e]];
    th1[e] = thrFB[m0 + 16 + Ml[e]];
  }
  float tm0 = fmaxf(fmaxf(th0[0],th0[1]), fmaxf(th0[2],th0[3]));
  float tm1 = fmaxf(fmaxf(th1[0],th1[1]), fmaxf(th1[2],th1[3]));

  __syncthreads();

  const int wcol = w*1024;
  const u16* bp = xtr16 + (size_t)(col0 + wcol + oprow)*DIM + kgrp*8;

#pragma unroll 2
  for (int jt = 0; jt < 64; ++jt){
    short8 b0 = *(const short8*)bp;
    short8 b1 = *(const short8*)(bp + 32);
    f32x4 c0 = {0.f,0.f,0.f,0.f}, c1 = {0.f,0.f,0.f,0.f};
    c0 = __builtin_amdgcn_mfma_f32_16x16x32_bf16(a00, b0, c0, 0,0,0);
    c0 = __builtin_amdgcn_mfma_f32_16x16x32_bf16(a01, b1, c0, 0,0,0);
    c1 = __builtin_amdgcn_mfma_f32_16x16x32_bf16(a10, b0, c1, 0,0,0);
    c1 = __builtin_amdgcn_mfma_f32_16x16x32_bf16(a11, b1, c1, 0,0,0);
    const int jl = wcol + jt*16;
    float h[4];
#pragma unroll
    for (int e = 0; e < 4; ++e) h[e] = hbS[jl + Jl[e]];
    float g0 = fmaxf(fmaxf(c0[0]-h[0], c0[1]-h[1]), fmaxf(c0[2]-h[2], c0[3]-h[3]));
    if (g0 + tm0 > 0.f){
#pragma unroll
      for (int e = 0; e < 4; ++e) if (h[e] - c0[e] < th0[e]){
        unsigned p = atomicAdd(&lcnt[Ml[e]], 1u);
        if (p < SLOT) lbuf[Ml[e]][p] = (u16)(jl + Jl[e]);
      }
    }
    float g1 = fmaxf(fmaxf(c1[0]-h[0], c1[1]-h[1]), fmaxf(c1[2]-h[2], c1[3]-h[3]));
    if (g1 + tm1 > 0.f){
#pragma unroll
      for (int e = 0; e < 4; ++e) if (h[e] - c1[e] < th1[e]){
        unsigned p = atomicAdd(&lcnt[16 + Ml[e]], 1u);
        if (p < SLOT) lbuf[16 + Ml[e]][p] = (u16)(jl + Jl[e]);
      }
    }
    bp += 16*DIM;
  }
  __syncthreads();
  if (t < 32) cnt2[(size_t)jc*NTEST + m0 + t] = lcnt[t];
  // flush u16 slots as packed dwords
  const unsigned* lb32 = (const unsigned*)lbuf;
  unsigned* c32 = (unsigned*)cand;
  for (int i = t; i < 32*(SLOT/2); i += 256){
    int ms = i / (SLOT/2), e = i - ms*(SLOT/2);
    c32[((size_t)(m0 + ms)*NCH + jc)*(SLOT/2) + e] = lb32[i];
  }
}

// ---- knnB: exact fp32 re-rank + verify + vote + argmax ----
__global__ __launch_bounds__(256) void knnB(const float* __restrict__ x_train,
        const float* __restrict__ hb2, const float* __restrict__ x_test,
        const int* __restrict__ y_train, const float* __restrict__ w_train,
        const float* __restrict__ TfB, const int* __restrict__ okf,
        const unsigned* __restrict__ cnt2, const u16* __restrict__ cand,
        int* __restrict__ out)
{
  __shared__ unsigned ku[POOLCAP], ki[POOLCAP];
  __shared__ unsigned chunkKeys[1024];
  __shared__ Sel ss;
  __shared__ unsigned tieI[256];
  __shared__ unsigned selI[40];
  __shared__ unsigned selR[KSEL];
  __shared__ int selCnt, tieCnt, poolCnt, nBelow, badJ;
  __shared__ float votes[NLAB];
  __shared__ unsigned cntS[NCH];
  __shared__ int yv[KSEL]; __shared__ float wv[KSEL];

  const int t = threadIdx.x, m = blockIdx.x;
  float a[DIM];
  const float4* am = (const float4*)(x_test + (size_t)m*DIM);
#pragma unroll
  for (int q = 0; q < 16; ++q){
    float4 v = am[q];
    a[4*q]=v.x; a[4*q+1]=v.y; a[4*q+2]=v.z; a[4*q+3]=v.w;
  }
  if (t < NCH) cntS[t] = cnt2[(size_t)t*NTEST + m];
  if (t == 0){ nBelow = 0; badJ = 0; }
  __syncthreads();

  bool ovf = (okf[0] == 0);
  unsigned offs[NCH+1]; offs[0] = 0;
#pragma unroll
  for (int jcc = 0; jcc < NCH; ++jcc){
    unsigned cc = cntS[jcc];
    if (cc > SLOT) ovf = true;
    offs[jcc+1] = offs[jcc] + ((cc > SLOT) ? SLOT : cc);
  }
  int c = (int)offs[NCH];
  bool mainok = !ovf && c >= KSEL;

  if (mainok){
#pragma unroll
    for (int jcc = 0; jcc < NCH; ++jcc){
      unsigned cc = cntS[jcc];
      for (unsigned i = t; i < cc; i += 256){
        unsigned v = cand[((size_t)m*NCH + jcc)*SLOT + i];
        if (v >= CHCOLS){ badJ = 1; v = 0; }
        ki[offs[jcc] + i] = (unsigned)(jcc*CHCOLS) + v;
      }
    }
    __syncthreads();
    if (badJ) mainok = false;
  }
  const float Tf = TfB[m];
  if (mainok){
    for (int i = t; i < c; i += 256){
      unsigned j = ki[i];
      const float4* rp = (const float4*)(x_train + (size_t)j*DIM);
      float s = 0.f;
#pragma unroll
      for (int q = 0; q < 16; ++q){
        float4 v = rp[q];
        s = fmaf(a[4*q],v.x,s); s = fmaf(a[4*q+1],v.y,s);
        s = fmaf(a[4*q+2],v.z,s); s = fmaf(a[4*q+3],v.w,s);
      }
      float kf = hb2[j] - s;
      ku[i] = f2u(kf);
      if (kf < Tf) atomicAdd(&nBelow, 1);
    }
    __syncthreads();
    mainok = (nBelow >= KSEL);   // guarantees global top-32 inside candidates
  }

  if (mainok){
    // all-pairs exact rank by (key asc, idx asc); deterministic slot-by-rank
    for (int i = t; i < c; i += 256){
      unsigned mu = ku[i], mi = ki[i];
      int r = 0;
      for (int k = 0; k < c; ++k){
        unsigned kk = ku[k], kj = ki[k];
        r += (kk < mu || (kk == mu && kj < mi)) ? 1 : 0;
      }
      if (r < KSEL) selR[r] = mi;
    }
    __syncthreads();
  } else {
    // fallback (safety net): exact full scan, chunk top-32 pooling
    if (t == 0) poolCnt = 0;
    __syncthreads();
    for (int ch = 0; ch < NTRAIN/1024; ++ch){
      const int j0 = ch*1024;
      for (int q = 0; q < 4; ++q){
        int j = j0 + q*256 + t;
        const float4* rp = (const float4*)(x_train + (size_t)j*DIM);
        float s = 0.f;
#pragma unroll
        for (int qq = 0; qq < 16; ++qq){
          float4 v = rp[qq];
          s = fmaf(a[4*qq],v.x,s); s = fmaf(a[4*qq+1],v.y,s);
          s = fmaf(a[4*qq+2],v.z,s); s = fmaf(a[4*qq+3],v.w,s);
        }
        chunkKeys[q*256 + t] = f2u(hb2[j] - s);
      }
      __syncthreads();
      int need;
      unsigned ustar = radix_select(chunkKeys, 1024, KSEL, &ss, t, &need);
      for (int q = 0; q < 4; ++q){
        unsigned u = chunkKeys[q*256 + t];
        if (u <= ustar){
          int p = atomicAdd(&poolCnt, 1);
          if (p < POOLCAP){ ku[p] = u; ki[p] = (unsigned)(j0 + q*256 + t); }
        }
      }
      __syncthreads();
    }
    int n = poolCnt; if (n > POOLCAP) n = POOLCAP;
    select32(ku, ki, n, &ss, tieI, selI, &selCnt, &tieCnt, t);
    if (t < KSEL) selR[t] = selI[t];
    __syncthreads();
  }

  // deterministic vote: reorder selected by train idx, then serial adds
  for (int q = t; q < NLAB; q += 256) votes[q] = 0.f;
  if (t < KSEL){
    unsigned my = selR[t]; int r = 0;
#pragma unroll
    for (int k = 0; k < KSEL; ++k) r += (selR[k] < my) ? 1 : 0;
    yv[r] = y_train[my]; wv[r] = w_train[my];
  }
  __syncthreads();
  if (t == 0){
    for (int r = 0; r < KSEL; ++r) votes[yv[r]] += wv[r];
  }
  __syncthreads();

  // argmax, lowest label wins ties
  float* rv = (float*)ss.hist;
  int*   rl = (int*)(ss.hist + 256);
  float bv = -1.f; int bl = 0;
  for (int l = t; l < NLAB; l += 256){
    float v = votes[l];
    if (v > bv){ bv = v; bl = l; }
  }
  rv[t] = bv; rl[t] = bl;
  __syncthreads();
  for (int sred = 128; sred > 0; sred >>= 1){
    if (t < sred){
      if (rv[t+sred] > rv[t] || (rv[t+sred] == rv[t] && rl[t+sred] < rl[t])){
        rv[t] = rv[t+sred]; rl[t] = rl[t+sred];
      }
    }
    __syncthreads();
  }
  if (t == 0) out[m] = rl[0];
}

// ---- legacy (direct-read path): used only if ws too small ----
__global__ __launch_bounds__(256) void knn_legacy(
    const float* __restrict__ x_train, const float* __restrict__ x_test,
    const int* __restrict__ y_train, const float* __restrict__ w_train,
    int* __restrict__ out)
{
  __shared__ unsigned keys[16384];
  __shared__ Sel ss;
  __shared__ unsigned candU[64];
  __shared__ unsigned candI[64];
  __shared__ unsigned tieI[256];
  __shared__ int nCand, nTie;
  __shared__ float rv[256]; __shared__ int rl[256];

  float* votes = (float*)ss.hist;
  const int t = threadIdx.x;
  const int m = blockIdx.x;

  float a[DIM];
  const float* am = x_test + (size_t)m * DIM;
#pragma unroll
  for (int d = 0; d < DIM; ++d) a[d] = am[d];

  if (t == 0) nCand = 0;

  for (int h = 0; h < 2; ++h){
    __syncthreads();
    for (int i = 0; i < 64; ++i){
      int j = h*16384 + i*256 + t;
      const float4* bp = (const float4*)(x_train + (size_t)j * DIM);
      float s = 0.f;
#pragma unroll
      for (int q = 0; q < 16; ++q){
        float4 v = bp[q];
        float e0 = a[4*q]   - v.x, e1 = a[4*q+1] - v.y;
        float e2 = a[4*q+2] - v.z, e3 = a[4*q+3] - v.w;
        s = fmaf(e0,e0,s); s = fmaf(e1,e1,s); s = fmaf(e2,e2,s); s = fmaf(e3,e3,s);
      }
      keys[i*256 + t] = f2u(s);
    }
    __syncthreads();

    int need;
    unsigned ustar = radix_select(keys, 16384, KSEL, &ss, t, &need);
    if (t == 0) nTie = 0;
    __syncthreads();

    for (int i = 0; i < 64; ++i){
      unsigned u   = keys[i*256 + t];
      unsigned idx = (unsigned)(h*16384 + i*256 + t);
      if (u < ustar){
        int p = atomicAdd(&nCand, 1);
        if (p < 64){ candU[p] = u; candI[p] = idx; }
      } else if (u == ustar){
        int p = atomicAdd(&nTie, 1);
        if (p < 256) tieI[p] = idx;
      }
    }
    __syncthreads();
    int nT = nTie; if (nT > 256) nT = 256;
    if (t < nT){
      unsigned my = tieI[t]; int r = 0;
      for (int k = 0; k < nT; ++k) r += (tieI[k] < my) ? 1 : 0;
      if (r < need){
        int p = atomicAdd(&nCand, 1);
        if (p < 64){ candU[p] = ustar; candI[p] = my; }
      }
    }
    __syncthreads();
  }

  for (int q = t; q < NLAB; q += 256) votes[q] = 0.f;
  __syncthreads();
  int nC = nCand; if (nC > 64) nC = 64;
  if (t < nC){
    unsigned mu = candU[t], mi = candI[t];
    int r = 0;
    for (int k = 0; k < nC; ++k){
      unsigned kku = candU[k], kki = candI[k];
      r += (kku < mu || (kku == mu && kki < mi)) ? 1 : 0;
    }
    if (r < KSEL){
      int lab = y_train[mi];
      atomicAdd(&votes[lab], w_train[mi]);
    }
  }
  __syncthreads();

  float bv = -1.f; int bl = 0;
  for (int l = t; l < NLAB; l += 256){
    float v = votes[l];
    if (v > bv){ bv = v; bl = l; }
  }
  rv[t] = bv; rl[t] = bl;
  __syncthreads();
  for (int s = 128; s > 0; s >>= 1){
    if (t < s){
      if (rv[t+s] > rv[t] || (rv[t+s] == rv[t] && rl[t+s] < rl[t])){
        rv[t] = rv[t+s]; rl[t] = rl[t+s];
      }
    }
    __syncthreads();
  }
  if (t == 0) out[m] = rl[0];
}

extern "C" void kernel_launch(void* const* d_in, const int* in_sizes, int n_in,
                              void* d_out, int out_size, void* d_ws, size_t ws_size,
                              hipStream_t stream)
{
  (void)in_sizes; (void)n_in; (void)out_size;
  const float* x_train = (const float*)d_in[0];
  const int*   y_train = (const int*)  d_in[1];
  const float* x_test  = (const float*)d_in[2];
  const float* w_train = (const float*)d_in[3];
  int* out = (int*)d_out;

  char* p = (char*)d_ws;
  u16*      xtr16  = (u16*)p;      p += (size_t)NTRAIN*DIM*2;
  u16*      xtst16 = (u16*)p;      p += (size_t)NTEST*DIM*2;
  float*    hb2    = (float*)p;    p += (size_t)NTRAIN*4;
  float*    loT    = (float*)p;    p += (size_t)NTEST*4;
  float*    bsT    = (float*)p;    p += (size_t)NTEST*4;
  float*    Wt     = (float*)p;    p += (size_t)NTEST*4;
  float*    TfB    = (float*)p;    p += (size_t)NTEST*4;
  float*    thrFB  = (float*)p;    p += (size_t)NTEST*4;
  unsigned* cnt2   = (unsigned*)p; p += (size_t)NCH*NTEST*4;
  int*      MT     = (int*)p;      p += 64*4*4;
  int*      JT     = (int*)p;      p += 64*4*4;
  int*      okf    = (int*)p;      p += 256;
  float*    stats  = (float*)p;    p += 512;
  u16*      cand   = (u16*)p;      p += (size_t)NTEST*NCH*SLOT*2;
  size_t need = (size_t)(p - (char*)d_ws);

  if (ws_size >= need){
    hipMemsetAsync(stats, 0, 512, stream);
    calib<<<1, 64, 0, stream>>>(MT, JT, okf);
    prep <<<NTRAIN/256, 256, 0, stream>>>(x_train, xtr16, hb2, stats);
    prepT<<<NTEST/256,  256, 0, stream>>>(x_test, xtst16, stats, loT, bsT, Wt);
    sampleT<<<NTEST/16, 256, 0, stream>>>(xtr16, xtst16, hb2, loT, bsT, Wt,
                                          MT, JT, okf, TfB, thrFB);
    knnA<<<(NTEST/32)*NCH, 256, 0, stream>>>(xtr16, xtst16, hb2, thrFB,
                                             MT, JT, okf, cnt2, cand);
    knnB<<<NTEST, 256, 0, stream>>>(x_train, hb2, x_test, y_train, w_train,
                                    TfB, okf, cnt2, cand, out);
  } else {
    knn_legacy<<<NTEST, 256, 0, stream>>>(x_train, x_test, y_train, w_train, out);
  }
}

// Round 9
// 304.255 us; speedup vs baseline: 2.9511x; 1.1094x over previous
//
#include <hip/hip_runtime.h>

#define NTRAIN 32768
#define NTEST  4096
#define DIM    64
#define KSEL   32
#define NLAB   1000
#define NCH    16       // j-chunks
#define CHCOLS 2048     // train cols per chunk
#define SLOT   112      // candidate slots per (test, chunk), u16 local idx
#define NBIN   256
#define SSAMP  8192     // sample size for threshold pass
#define SRANK2 32       // >= KSEL: deterministic verification guarantee
#define POOLCAP 1792    // >= NCH*SLOT
#define WCOEF  0.01f    // >= 0.0078 bf16 Cauchy-Schwarz bound + margin

using short8 = __attribute__((ext_vector_type(8))) short;
using f32x4  = __attribute__((ext_vector_type(4))) float;
typedef unsigned short u16;

__device__ __forceinline__ unsigned f2u(float f){
  unsigned b = __float_as_uint(f);
  return (b & 0x80000000u) ? ~b : (b | 0x80000000u);
}
// fp32 -> bf16 round-to-nearest-even
__device__ __forceinline__ u16 f2b(float x){
  unsigned u = __float_as_uint(x);
  return (u16)((u + 0x7fffu + ((u >> 16) & 1u)) >> 16);
}

struct Sel {
  unsigned hist[2048];
  unsigned wsum[4];
  unsigned sB, sLess, sU;
  int sNeed;
};

// exact value of the rank-th smallest key (1-based) among keys[0..n). n>=rank.
__device__ unsigned radix_select(const unsigned* __restrict__ keys, int n,
                                 unsigned rank, Sel* s, int t, int* needOut)
{
  const int lane = t & 63, wid = t >> 6;
  unsigned target = rank, pref = 0;
  for (int lev = 0; lev < 3; ++lev){
    const int nb    = (lev == 2) ? 1024 : 2048;
    const int shift = (lev == 0) ? 21 : (lev == 1 ? 10 : 0);
    for (int q = t; q < nb; q += 256) s->hist[q] = 0;
    __syncthreads();
    for (int i = t; i < n; i += 256){
      unsigned u = keys[i];
      bool ok = (lev == 0) ? true
              : (lev == 1) ? ((u >> 21) == pref)
                           : ((u >> 10) == pref);
      if (ok) atomicAdd(&s->hist[(u >> shift) & (unsigned)(nb - 1)], 1u);
    }
    __syncthreads();
    const int g = nb / 256;
    unsigned sl = 0;
#pragma unroll
    for (int k = 0; k < 8; ++k) if (k < g) sl += s->hist[t*g + k];
    unsigned x = sl;
#pragma unroll
    for (int ofs = 1; ofs < 64; ofs <<= 1){
      unsigned v = __shfl_up(x, (unsigned)ofs, 64);
      if (lane >= ofs) x += v;
    }
    if (lane == 63) s->wsum[wid] = x;
    __syncthreads();
    unsigned woff = 0;
#pragma unroll
    for (int w = 0; w < 4; ++w) if (w < wid) woff += s->wsum[w];
    unsigned incl = x + woff;
    unsigned excl = incl - sl;
    if (excl < target && target <= incl){
      unsigned cum = excl; int b = t*g;
      while (cum + s->hist[b] < target){ cum += s->hist[b]; ++b; }
      s->sB = (unsigned)b; s->sLess = cum;
    }
    __syncthreads();
    unsigned B = s->sB, cl = s->sLess;
    target -= cl;
    if      (lev == 0) pref = B;
    else if (lev == 1) pref = (pref << 11) | B;
    else if (t == 0){ s->sU = (pref << 10) | B; s->sNeed = (int)target; }
  }
  __syncthreads();
  *needOut = s->sNeed;
  return s->sU;
}

// exact top-KSEL among (ku,ki)[0..n) by (key asc, idx asc). n>=KSEL. writes selI.
__device__ void select32(const unsigned* ku, const unsigned* ki, int n,
                         Sel* s, unsigned* tieI, unsigned* selI,
                         int* selCnt, int* tieCnt, int t)
{
  int need;
  unsigned ustar = radix_select(ku, n, KSEL, s, t, &need);
  if (t == 0){ *selCnt = 0; *tieCnt = 0; }
  __syncthreads();
  for (int i = t; i < n; i += 256){
    unsigned u = ku[i];
    if (u < ustar){ int p = atomicAdd(selCnt, 1); if (p < 40) selI[p] = ki[i]; }
    else if (u == ustar){ int p = atomicAdd(tieCnt, 1); if (p < 256) tieI[p] = ki[i]; }
  }
  __syncthreads();
  int nT = *tieCnt; if (nT > 256) nT = 256;
  if (t < nT){
    unsigned my = tieI[t]; int r = 0;
    for (int k = 0; k < nT; ++k) r += (tieI[k] < my) ? 1 : 0;
    if (r < need){ int p = atomicAdd(selCnt, 1); if (p < 40) selI[p] = my; }
  }
  __syncthreads();
}

// ---- calib: measure MFMA output-slot -> (A-index, B-index) mapping ----
__global__ void calib(int* __restrict__ MT, int* __restrict__ JT,
                      int* __restrict__ okf)
{
  const int l = threadIdx.x;          // 64 threads = 1 wave
  const int v = l & 15;
  short8 av, onev, kv;
  u16 vb  = f2b((float)(v + 1));
  u16 one = (u16)0x3F80;
#pragma unroll
  for (int e = 0; e < 8; ++e){
    ((u16*)&av)[e]   = vb;
    ((u16*)&onev)[e] = one;
    ((u16*)&kv)[e]   = f2b((float)((l >> 4)*8 + e + 1));
  }
  f32x4 dA = {0,0,0,0}, dB = {0,0,0,0}, dK = {0,0,0,0};
  dA = __builtin_amdgcn_mfma_f32_16x16x32_bf16(av, onev, dA, 0,0,0);
  dB = __builtin_amdgcn_mfma_f32_16x16x32_bf16(onev, av, dB, 0,0,0);
  dK = __builtin_amdgcn_mfma_f32_16x16x32_bf16(kv, kv, dK, 0,0,0);
  bool ok = true;
#pragma unroll
  for (int e = 0; e < 4; ++e){
    int mi = (int)(dA[e]*(1.0f/32.0f) + 0.5f) - 1;
    int ji = (int)(dB[e]*(1.0f/32.0f) + 0.5f) - 1;
    if (mi < 0 || mi > 15 || dA[e] != 32.0f*(float)(mi+1)) ok = false;
    if (ji < 0 || ji > 15 || dB[e] != 32.0f*(float)(ji+1)) ok = false;
    if (dK[e] != 11440.0f) ok = false;
    MT[l*4 + e] = mi & 15;
    JT[l*4 + e] = ji & 15;
  }
  unsigned long long bal = __ballot(ok);
  if (l == 0) okf[0] = (bal == ~0ull) ? 1 : 0;
}

// ---- prep: x_train -> bf16 + hb2 = 0.5*||b||^2 + stats {sum, sumsq, maxb2} ----
__global__ __launch_bounds__(256) void prep(const float* __restrict__ xtr,
        u16* __restrict__ xtr16, float* __restrict__ hb2,
        float* __restrict__ stats)
{
  int j = blockIdx.x*256 + threadIdx.x;
  const float4* rp = (const float4*)(xtr + (size_t)j*DIM);
  u16* orow = xtr16 + (size_t)j*DIM;
  float s = 0.f;
#pragma unroll
  for (int q = 0; q < 16; ++q){
    float4 w = rp[q];
    uint2 pk;
    pk.x = (unsigned)f2b(w.x) | ((unsigned)f2b(w.y) << 16);
    pk.y = (unsigned)f2b(w.z) | ((unsigned)f2b(w.w) << 16);
    *(uint2*)(orow + q*4) = pk;
    s = fmaf(w.x,w.x,s); s = fmaf(w.y,w.y,s);
    s = fmaf(w.z,w.z,s); s = fmaf(w.w,w.w,s);
  }
  float hs = 0.5f * s;
  hb2[j] = hs;
  float r0 = hs, r1 = hs*hs, r2 = s;
#pragma unroll
  for (int msk = 1; msk < 64; msk <<= 1){
    r0 += __shfl_xor(r0, msk, 64);
    r1 += __shfl_xor(r1, msk, 64);
    r2 = fmaxf(r2, __shfl_xor(r2, msk, 64));
  }
  if ((threadIdx.x & 63) == 0){
    atomicAdd(&stats[0], r0);
    atomicAdd(&stats[1], r1);
    atomicMax((unsigned*)&stats[2], __float_as_uint(r2));
  }
}

// ---- prepT: x_test -> bf16 + per-test binning params lo/scale + W ----
__global__ __launch_bounds__(256) void prepT(const float* __restrict__ xtst,
        u16* __restrict__ xtst16, const float* __restrict__ stats,
        float* __restrict__ loT, float* __restrict__ bsT, float* __restrict__ Wt)
{
  int m = blockIdx.x*256 + threadIdx.x;
  const float4* rp = (const float4*)(xtst + (size_t)m*DIM);
  u16* orow = xtst16 + (size_t)m*DIM;
  float s = 0.f;
#pragma unroll
  for (int q = 0; q < 16; ++q){
    float4 w = rp[q];
    uint2 pk;
    pk.x = (unsigned)f2b(w.x) | ((unsigned)f2b(w.y) << 16);
    pk.y = (unsigned)f2b(w.z) | ((unsigned)f2b(w.w) << 16);
    *(uint2*)(orow + q*4) = pk;
    s = fmaf(w.x,w.x,s); s = fmaf(w.y,w.y,s);
    s = fmaf(w.z,w.z,s); s = fmaf(w.w,w.w,s);
  }
  const float invN = 1.0f/(float)NTRAIN;
  float C   = stats[0]*invN;
  float var = fmaxf(stats[1]*invN - C*C, 0.f);
  float mb  = __uint_as_float(*(const unsigned*)&stats[2]);
  float sig = sqrtf(var + s) + 1e-6f;
  loT[m] = C - 12.f*sig;
  bsT[m] = 16.f/sig;               // 256 bins spanning 16*sig
  Wt[m]  = WCOEF * sqrtf(s * mb);
}

// ---- sampleT: per-test threshold from first SSAMP train pts (MFMA + LDS hist,
//      skip-cutoff so only ~2-3% of keys take an LDS atomic).
//      SRANK2 >= KSEL -> deterministic verification guarantee in knnB. ----
__global__ __launch_bounds__(256) void sampleT(const u16* __restrict__ xtr16,
        const u16* __restrict__ xtst16, const float* __restrict__ hb2,
        const float* __restrict__ loT, const float* __restrict__ bsT,
        const float* __restrict__ Wt, const int* __restrict__ MT,
        const int* __restrict__ JT, const int* __restrict__ okf,
        float* __restrict__ TfB, float* __restrict__ thrFB)
{
  __shared__ unsigned histL[16*NBIN];   // 16 KB
  __shared__ float hbS[SSAMP];          // 32 KB

  const int t = threadIdx.x, lane = t & 63, w = t >> 6;
  const int m0 = blockIdx.x * 16;
  if (okf[0] == 0){
    if (t < 16){ TfB[m0+t] = 0.f; thrFB[m0+t] = -3.0e38f; }   // -> fallback
    return;
  }
  const int oprow = lane & 15, kgrp = lane >> 4;

  for (int i = t; i < 16*NBIN; i += 256) histL[i] = 0;
  for (int i = t; i < SSAMP; i += 256) hbS[i] = hb2[i];

  int Ml[4], Jl[4];
#pragma unroll
  for (int e = 0; e < 4; ++e){ Ml[e] = MT[lane*4+e]; Jl[e] = JT[lane*4+e]; }

  const u16* ap = xtst16 + (size_t)(m0 + oprow)*DIM + kgrp*8;
  short8 a00 = *(const short8*)ap;
  short8 a01 = *(const short8*)(ap + 32);

  float lo0[4], bs0[4];
#pragma unroll
  for (int e = 0; e < 4; ++e){
    lo0[e] = loT[m0 + Ml[e]]; bs0[e] = bsT[m0 + Ml[e]];
  }
  __syncthreads();

  const int wcol = w*(SSAMP/4);
  const u16* bp = xtr16 + (size_t)(wcol + oprow)*DIM + kgrp*8;

#pragma unroll 2
  for (int jt = 0; jt < SSAMP/64; ++jt){
    short8 b0 = *(const short8*)bp;
    short8 b1 = *(const short8*)(bp + 32);
    f32x4 c0 = {0.f,0.f,0.f,0.f};
    c0 = __builtin_amdgcn_mfma_f32_16x16x32_bf16(a00, b0, c0, 0,0,0);
    c0 = __builtin_amdgcn_mfma_f32_16x16x32_bf16(a01, b1, c0, 0,0,0);
    const int jl = wcol + jt*16;
#pragma unroll
    for (int e = 0; e < 4; ++e){
      float h = hbS[jl + Jl[e]];
      float f = (h - c0[e] - lo0[e]) * bs0[e];
      if (f < 161.f){                         // skip: bins >160 can't matter
        int b = (f < 0.f) ? 0 : (int)f;
        atomicAdd(&histL[Ml[e]*NBIN + b], 1u);
      }
    }
    bp += 16*DIM;
  }
  __syncthreads();
  if (t < 16){
    const unsigned* h = &histL[t*NBIN];
    unsigned cum = 0; int b = -1;
    for (int i = 0; i <= 160; ++i){
      cum += h[i];
      if (cum >= SRANK2){ b = i; break; }
    }
    int m = m0 + t;
    if (b < 0){ TfB[m] = 0.f; thrFB[m] = -3.0e38f; }   // -> empty -> fallback
    else {
      float Te = loT[m] + (float)(b + 1) / bsT[m];
      float Wv = Wt[m];
      TfB[m]   = Te + 1.5f*Wv;
      thrFB[m] = Te + 2.5f*Wv;
    }
  }
}

// ---- knnA: MFMA filter, u16 LDS slot buffers, zero global atomics ----
__global__ __launch_bounds__(256) void knnA(const u16* __restrict__ xtr16,
        const u16* __restrict__ xtst16, const float* __restrict__ hb2,
        const float* __restrict__ thrFB, const int* __restrict__ MT,
        const int* __restrict__ JT, const int* __restrict__ okf,
        unsigned* __restrict__ cnt2, u16* __restrict__ cand)
{
  __shared__ float hbS[CHCOLS];          // 8 KB
  __shared__ u16 lbuf[32][SLOT];         // 7 KB
  __shared__ unsigned lcnt[32];

  const int t = threadIdx.x, lane = t & 63, w = t >> 6;
  const int jc = blockIdx.x & (NCH-1), mg = blockIdx.x >> 4;
  const int m0 = mg*32, col0 = jc*CHCOLS;

  if (okf[0] == 0){
    if (t < 32) cnt2[(size_t)jc*NTEST + m0 + t] = 0xFFFFFFFFu;  // force fallback
    return;
  }
  const int oprow = lane & 15, kgrp = lane >> 4;

  if (t < 32) lcnt[t] = 0;
  for (int i = t; i < CHCOLS; i += 256) hbS[i] = hb2[col0 + i];

  int Ml[4], Jl[4];
#pragma unroll
  for (int e = 0; e < 4; ++e){ Ml[e] = MT[lane*4+e]; Jl[e] = JT[lane*4+e]; }

  const u16* ap = xtst16 + (size_t)(m0 + oprow)*DIM + kgrp*8;
  short8 a00 = *(const short8*)ap;
  short8 a01 = *(const short8*)(ap + 32);
  short8 a10 = *(const short8*)(ap + 16*DIM);
  short8 a11 = *(const short8*)(ap + 16*DIM + 32);

  float th0[4], th1[4];
#pragma unroll
  for (int e = 0; e < 4; ++e){
    th0[e] = thrFB[m0 + Ml[e]];
    th1[e] = thrFB[m0 + 16 + Ml[e]];
  }
  float tm0 = fmaxf(fmaxf(th0[0],th0[1]), fmaxf(th0[2],th0[3]));
  float tm1 = fmaxf(fmaxf(th1[0],th1[1]), fmaxf(th1[2],th1[3]));

  __syncthreads();

  const int wcol = w*(CHCOLS/4);
  const u16* bp = xtr16 + (size_t)(col0 + wcol + oprow)*DIM + kgrp*8;

#pragma unroll 2
  for (int jt = 0; jt < CHCOLS/64; ++jt){
    short8 b0 = *(const short8*)bp;
    short8 b1 = *(const short8*)(bp + 32);
    f32x4 c0 = {0.f,0.f,0.f,0.f}, c1 = {0.f,0.f,0.f,0.f};
    c0 = __builtin_amdgcn_mfma_f32_16x16x32_bf16(a00, b0, c0, 0,0,0);
    c0 = __builtin_amdgcn_mfma_f32_16x16x32_bf16(a01, b1, c0, 0,0,0);
    c1 = __builtin_amdgcn_mfma_f32_16x16x32_bf16(a10, b0, c1, 0,0,0);
    c1 = __builtin_amdgcn_mfma_f32_16x16x32_bf16(a11, b1, c1, 0,0,0);
    const int jl = wcol + jt*16;
    float h[4];
#pragma unroll
    for (int e = 0; e < 4; ++e) h[e] = hbS[jl + Jl[e]];
    float g0 = fmaxf(fmaxf(c0[0]-h[0], c0[1]-h[1]), fmaxf(c0[2]-h[2], c0[3]-h[3]));
    if (g0 + tm0 > 0.f){
#pragma unroll
      for (int e = 0; e < 4; ++e) if (h[e] - c0[e] < th0[e]){
        unsigned p = atomicAdd(&lcnt[Ml[e]], 1u);
        if (p < SLOT) lbuf[Ml[e]][p] = (u16)(jl + Jl[e]);
      }
    }
    float g1 = fmaxf(fmaxf(c1[0]-h[0], c1[1]-h[1]), fmaxf(c1[2]-h[2], c1[3]-h[3]));
    if (g1 + tm1 > 0.f){
#pragma unroll
      for (int e = 0; e < 4; ++e) if (h[e] - c1[e] < th1[e]){
        unsigned p = atomicAdd(&lcnt[16 + Ml[e]], 1u);
        if (p < SLOT) lbuf[16 + Ml[e]][p] = (u16)(jl + Jl[e]);
      }
    }
    bp += 16*DIM;
  }
  __syncthreads();
  if (t < 32) cnt2[(size_t)jc*NTEST + m0 + t] = lcnt[t];
  // flush u16 slots as packed dwords
  const unsigned* lb32 = (const unsigned*)lbuf;
  unsigned* c32 = (unsigned*)cand;
  for (int i = t; i < 32*(SLOT/2); i += 256){
    int ms = i / (SLOT/2), e = i - ms*(SLOT/2);
    c32[((size_t)(m0 + ms)*NCH + jc)*(SLOT/2) + e] = lb32[i];
  }
}

// ---- knnB: exact fp32 re-rank + verify + O(c) radix select + vote + argmax ----
__global__ __launch_bounds__(256) void knnB(const float* __restrict__ x_train,
        const float* __restrict__ hb2, const float* __restrict__ x_test,
        const int* __restrict__ y_train, const float* __restrict__ w_train,
        const float* __restrict__ TfB, const int* __restrict__ okf,
        const unsigned* __restrict__ cnt2, const u16* __restrict__ cand,
        int* __restrict__ out)
{
  __shared__ unsigned ku[POOLCAP], ki[POOLCAP];
  __shared__ unsigned chunkKeys[1024];
  __shared__ Sel ss;
  __shared__ unsigned tieI[256];
  __shared__ unsigned selI[40];
  __shared__ unsigned selR[KSEL];
  __shared__ int selCnt, tieCnt, poolCnt, nBelow, badJ;
  __shared__ float votes[NLAB];
  __shared__ unsigned cntS[NCH];
  __shared__ int yv[KSEL]; __shared__ float wv[KSEL];

  const int t = threadIdx.x, m = blockIdx.x;
  float a[DIM];
  const float4* am = (const float4*)(x_test + (size_t)m*DIM);
#pragma unroll
  for (int q = 0; q < 16; ++q){
    float4 v = am[q];
    a[4*q]=v.x; a[4*q+1]=v.y; a[4*q+2]=v.z; a[4*q+3]=v.w;
  }
  if (t < NCH) cntS[t] = cnt2[(size_t)t*NTEST + m];
  if (t == 0){ nBelow = 0; badJ = 0; }
  __syncthreads();

  bool ovf = (okf[0] == 0);
  unsigned offs[NCH+1]; offs[0] = 0;
#pragma unroll
  for (int jcc = 0; jcc < NCH; ++jcc){
    unsigned cc = cntS[jcc];
    if (cc > SLOT) ovf = true;
    offs[jcc+1] = offs[jcc] + ((cc > SLOT) ? SLOT : cc);
  }
  int c = (int)offs[NCH];
  bool mainok = !ovf && c >= KSEL;

  if (mainok){
#pragma unroll
    for (int jcc = 0; jcc < NCH; ++jcc){
      unsigned cc = cntS[jcc];
      for (unsigned i = t; i < cc; i += 256){
        unsigned v = cand[((size_t)m*NCH + jcc)*SLOT + i];
        if (v >= CHCOLS){ badJ = 1; v = 0; }
        ki[offs[jcc] + i] = (unsigned)(jcc*CHCOLS) + v;
      }
    }
    __syncthreads();
    if (badJ) mainok = false;
  }
  const float Tf = TfB[m];
  if (mainok){
    for (int i = t; i < c; i += 256){
      unsigned j = ki[i];
      const float4* rp = (const float4*)(x_train + (size_t)j*DIM);
      float s = 0.f;
#pragma unroll
      for (int q = 0; q < 16; ++q){
        float4 v = rp[q];
        s = fmaf(a[4*q],v.x,s); s = fmaf(a[4*q+1],v.y,s);
        s = fmaf(a[4*q+2],v.z,s); s = fmaf(a[4*q+3],v.w,s);
      }
      float kf = hb2[j] - s;
      ku[i] = f2u(kf);
      if (kf < Tf) atomicAdd(&nBelow, 1);
    }
    __syncthreads();
    mainok = (nBelow >= KSEL);   // guarantees global top-32 inside candidates
  }

  if (mainok){
    // O(c) exact top-32: radix select + lowest-index tie resolution
    select32(ku, ki, c, &ss, tieI, selI, &selCnt, &tieCnt, t);
    if (t < KSEL) selR[t] = selI[t];
    __syncthreads();
  } else {
    // fallback (safety net): exact full scan, chunk top-32 pooling
    if (t == 0) poolCnt = 0;
    __syncthreads();
    for (int ch = 0; ch < NTRAIN/1024; ++ch){
      const int j0 = ch*1024;
      for (int q = 0; q < 4; ++q){
        int j = j0 + q*256 + t;
        const float4* rp = (const float4*)(x_train + (size_t)j*DIM);
        float s = 0.f;
#pragma unroll
        for (int qq = 0; qq < 16; ++qq){
          float4 v = rp[qq];
          s = fmaf(a[4*qq],v.x,s); s = fmaf(a[4*qq+1],v.y,s);
          s = fmaf(a[4*qq+2],v.z,s); s = fmaf(a[4*qq+3],v.w,s);
        }
        chunkKeys[q*256 + t] = f2u(hb2[j] - s);
      }
      __syncthreads();
      int need;
      unsigned ustar = radix_select(chunkKeys, 1024, KSEL, &ss, t, &need);
      for (int q = 0; q < 4; ++q){
        unsigned u = chunkKeys[q*256 + t];
        if (u <= ustar){
          int p = atomicAdd(&poolCnt, 1);
          if (p < POOLCAP){ ku[p] = u; ki[p] = (unsigned)(j0 + q*256 + t); }
        }
      }
      __syncthreads();
    }
    int n = poolCnt; if (n > POOLCAP) n = POOLCAP;
    select32(ku, ki, n, &ss, tieI, selI, &selCnt, &tieCnt, t);
    if (t < KSEL) selR[t] = selI[t];
    __syncthreads();
  }

  // deterministic vote: reorder selected by train idx, then serial adds
  for (int q = t; q < NLAB; q += 256) votes[q] = 0.f;
  if (t < KSEL){
    unsigned my = selR[t]; int r = 0;
#pragma unroll
    for (int k = 0; k < KSEL; ++k) r += (selR[k] < my) ? 1 : 0;
    yv[r] = y_train[my]; wv[r] = w_train[my];
  }
  __syncthreads();
  if (t == 0){
    for (int r = 0; r < KSEL; ++r) votes[yv[r]] += wv[r];
  }
  __syncthreads();

  // argmax, lowest label wins ties
  float* rv = (float*)ss.hist;
  int*   rl = (int*)(ss.hist + 256);
  float bv = -1.f; int bl = 0;
  for (int l = t; l < NLAB; l += 256){
    float v = votes[l];
    if (v > bv){ bv = v; bl = l; }
  }
  rv[t] = bv; rl[t] = bl;
  __syncthreads();
  for (int sred = 128; sred > 0; sred >>= 1){
    if (t < sred){
      if (rv[t+sred] > rv[t] || (rv[t+sred] == rv[t] && rl[t+sred] < rl[t])){
        rv[t] = rv[t+sred]; rl[t] = rl[t+sred];
      }
    }
    __syncthreads();
  }
  if (t == 0) out[m] = rl[0];
}

// ---- legacy (direct-read path): used only if ws too small ----
__global__ __launch_bounds__(256) void knn_legacy(
    const float* __restrict__ x_train, const float* __restrict__ x_test,
    const int* __restrict__ y_train, const float* __restrict__ w_train,
    int* __restrict__ out)
{
  __shared__ unsigned keys[16384];
  __shared__ Sel ss;
  __shared__ unsigned candU[64];
  __shared__ unsigned candI[64];
  __shared__ unsigned tieI[256];
  __shared__ int nCand, nTie;
  __shared__ float rv[256]; __shared__ int rl[256];

  float* votes = (float*)ss.hist;
  const int t = threadIdx.x;
  const int m = blockIdx.x;

  float a[DIM];
  const float* am = x_test + (size_t)m * DIM;
#pragma unroll
  for (int d = 0; d < DIM; ++d) a[d] = am[d];

  if (t == 0) nCand = 0;

  for (int h = 0; h < 2; ++h){
    __syncthreads();
    for (int i = 0; i < 64; ++i){
      int j = h*16384 + i*256 + t;
      const float4* bp = (const float4*)(x_train + (size_t)j * DIM);
      float s = 0.f;
#pragma unroll
      for (int q = 0; q < 16; ++q){
        float4 v = bp[q];
        float e0 = a[4*q]   - v.x, e1 = a[4*q+1] - v.y;
        float e2 = a[4*q+2] - v.z, e3 = a[4*q+3] - v.w;
        s = fmaf(e0,e0,s); s = fmaf(e1,e1,s); s = fmaf(e2,e2,s); s = fmaf(e3,e3,s);
      }
      keys[i*256 + t] = f2u(s);
    }
    __syncthreads();

    int need;
    unsigned ustar = radix_select(keys, 16384, KSEL, &ss, t, &need);
    if (t == 0) nTie = 0;
    __syncthreads();

    for (int i = 0; i < 64; ++i){
      unsigned u   = keys[i*256 + t];
      unsigned idx = (unsigned)(h*16384 + i*256 + t);
      if (u < ustar){
        int p = atomicAdd(&nCand, 1);
        if (p < 64){ candU[p] = u; candI[p] = idx; }
      } else if (u == ustar){
        int p = atomicAdd(&nTie, 1);
        if (p < 256) tieI[p] = idx;
      }
    }
    __syncthreads();
    int nT = nTie; if (nT > 256) nT = 256;
    if (t < nT){
      unsigned my = tieI[t]; int r = 0;
      for (int k = 0; k < nT; ++k) r += (tieI[k] < my) ? 1 : 0;
      if (r < need){
        int p = atomicAdd(&nCand, 1);
        if (p < 64){ candU[p] = ustar; candI[p] = my; }
      }
    }
    __syncthreads();
  }

  for (int q = t; q < NLAB; q += 256) votes[q] = 0.f;
  __syncthreads();
  int nC = nCand; if (nC > 64) nC = 64;
  if (t < nC){
    unsigned mu = candU[t], mi = candI[t];
    int r = 0;
    for (int k = 0; k < nC; ++k){
      unsigned kku = candU[k], kki = candI[k];
      r += (kku < mu || (kku == mu && kki < mi)) ? 1 : 0;
    }
    if (r < KSEL){
      int lab = y_train[mi];
      atomicAdd(&votes[lab], w_train[mi]);
    }
  }
  __syncthreads();

  float bv = -1.f; int bl = 0;
  for (int l = t; l < NLAB; l += 256){
    float v = votes[l];
    if (v > bv){ bv = v; bl = l; }
  }
  rv[t] = bv; rl[t] = bl;
  __syncthreads();
  for (int s = 128; s > 0; s >>= 1){
    if (t < s){
      if (rv[t+s] > rv[t] || (rv[t+s] == rv[t] && rl[t+s] < rl[t])){
        rv[t] = rv[t+s]; rl[t] = rl[t+s];
      }
    }
    __syncthreads();
  }
  if (t == 0) out[m] = rl[0];
}

extern "C" void kernel_launch(void* const* d_in, const int* in_sizes, int n_in,
                              void* d_out, int out_size, void* d_ws, size_t ws_size,
                              hipStream_t stream)
{
  (void)in_sizes; (void)n_in; (void)out_size;
  const float* x_train = (const float*)d_in[0];
  const int*   y_train = (const int*)  d_in[1];
  const float* x_test  = (const float*)d_in[2];
  const float* w_train = (const float*)d_in[3];
  int* out = (int*)d_out;

  char* p = (char*)d_ws;
  u16*      xtr16  = (u16*)p;      p += (size_t)NTRAIN*DIM*2;
  u16*      xtst16 = (u16*)p;      p += (size_t)NTEST*DIM*2;
  float*    hb2    = (float*)p;    p += (size_t)NTRAIN*4;
  float*    loT    = (float*)p;    p += (size_t)NTEST*4;
  float*    bsT    = (float*)p;    p += (size_t)NTEST*4;
  float*    Wt     = (float*)p;    p += (size_t)NTEST*4;
  float*    TfB    = (float*)p;    p += (size_t)NTEST*4;
  float*    thrFB  = (float*)p;    p += (size_t)NTEST*4;
  unsigned* cnt2   = (unsigned*)p; p += (size_t)NCH*NTEST*4;
  int*      MT     = (int*)p;      p += 64*4*4;
  int*      JT     = (int*)p;      p += 64*4*4;
  int*      okf    = (int*)p;      p += 256;
  float*    stats  = (float*)p;    p += 512;
  u16*      cand   = (u16*)p;      p += (size_t)NTEST*NCH*SLOT*2;
  size_t need = (size_t)(p - (char*)d_ws);

  if (ws_size >= need){
    hipMemsetAsync(stats, 0, 512, stream);
    calib<<<1, 64, 0, stream>>>(MT, JT, okf);
    prep <<<NTRAIN/256, 256, 0, stream>>>(x_train, xtr16, hb2, stats);
    prepT<<<NTEST/256,  256, 0, stream>>>(x_test, xtst16, stats, loT, bsT, Wt);
    sampleT<<<NTEST/16, 256, 0, stream>>>(xtr16, xtst16, hb2, loT, bsT, Wt,
                                          MT, JT, okf, TfB, thrFB);
    knnA<<<(NTEST/32)*NCH, 256, 0, stream>>>(xtr16, xtst16, hb2, thrFB,
                                             MT, JT, okf, cnt2, cand);
    knnB<<<NTEST, 256, 0, stream>>>(x_train, hb2, x_test, y_train, w_train,
                                    TfB, okf, cnt2, cand, out);
  } else {
    knn_legacy<<<NTEST, 256, 0, stream>>>(x_train, x_test, y_train, w_train, out);
  }
}